// Round 3
// baseline (314.872 us; speedup 1.0000x reference)
//
#include <hip/hip_runtime.h>

// SobelLoss R3b: continuously-streaming row-sliding stencil (no LDS, no barriers).
//
// R2 was latency-bound: loads in flight only ~30% of the time (stage->barrier->
// compute phases), matching the measured 30% HBM utilization, with 1.4e7 LDS
// bank-conflict cycles on top. This version keeps a 3-row separable-Sobel
// window in registers, prefetches the next row into A/B register buffers while
// computing the current row, and gets horizontal neighbors via __shfl (wave
// edges via 2-lane predicated loads). Loads are outstanding continuously.
//
// Layout: x[img][h][w][f], f innermost (8 floats = 32B per pixel).
// Lane = (pixel, q): lane>>1 = pixel in wave's 32-pixel span, lane&1 = which
// float4 half -> per-row wave load = 64 lanes * 16B contiguous = 1KB, coalesced.
// Separable Sobel: hx = dR - dL, hs = dL + 2d + dR per row;
//   gx(r) = hx(r-1) + 2 hx(r) + hx(r+1), gy(r) = hs(r+1) - hs(r-1).
// valid = AND of 3x3 mask (== conv(mask,ones)==9); borders forced 0 (zero-pad
// can never reach 9), so clamped halo loads are harmless.

constexpr int H = 512, W = 512, F = 8;
constexpr int IMAGES = 12;            // B*T
constexpr int SH = 8;                 // output rows per strip
constexpr int STRIPS = H / SH;        // 64
constexpr int NIT = SH + 2;           // staged rows per strip (halo = 2)

typedef float f32x4 __attribute__((ext_vector_type(4)));

__global__ __launch_bounds__(256, 4) void sobel_loss_kernel(
    const float* __restrict__ pred,
    const float* __restrict__ tgt,
    const int*   __restrict__ mask,
    float*       __restrict__ out)
{
    const int tid  = threadIdx.x;
    const int lane = tid & 63;
    const int wid  = tid >> 6;

    const int bid   = blockIdx.x;
    const int img   = bid >> 8;           // 4*64 = 256 blocks per image
    const int rest  = bid & 255;
    const int quad  = rest & 3;           // quarter of the row (128 pixels)
    const int strip = rest >> 2;          // 0..63
    const int h0    = strip * SH;

    const int p = lane >> 1;              // pixel within wave's 32-pixel span
    const int q = lane & 1;               // float4 half of the pixel
    const int w = (quad * 4 + wid) * 32 + p;

    const size_t ibase = (size_t)img * ((size_t)H * W * F);
    const int voff = w * F + q * 4;       // per-lane float offset in a row
    const bool eL = (p == 0);
    const bool eR = (p == 31);
    const bool edge = eL || eR;
    const int wn   = eL ? (w > 0 ? w - 1 : 0) : (w < W - 1 ? w + 1 : W - 1);
    const int eoff = wn * F + q * 4;
    const bool win = (w > 0) & (w < W - 1);

    float4 bp[2], bt[2]; int4 bm[2];      // A/B prefetch buffers (own pixel)
    float4 bep[2], bet[2]; int4 bem[2];   // A/B prefetch buffers (edge-lane neighbor)
    float4 hx[3], hs[3]; unsigned hm[3];  // 3-row sliding window

    // Defined values on non-edge lanes (never used there, but avoid undef).
    bep[0] = bep[1] = bet[0] = bet[1] = make_float4(0.f, 0.f, 0.f, 0.f);
    bem[0] = bem[1] = make_int4(0, 0, 0, 0);

#define SUB4(a, b) make_float4((a).x - (b).x, (a).y - (b).y, (a).z - (b).z, (a).w - (b).w)

#define PREFETCH(NB, HNX)                                                     \
    {                                                                         \
        const int hraw = (HNX);                                               \
        const int hc = hraw < 0 ? 0 : (hraw >= H ? H - 1 : hraw);             \
        const size_t ro = ibase + (size_t)hc * (W * F);                       \
        bp[NB] = *(const float4*)(pred + ro + voff);                          \
        bt[NB] = *(const float4*)(tgt  + ro + voff);                          \
        bm[NB] = *(const int4*)(mask + ro + voff);                            \
        if (edge) {                                                           \
            bep[NB] = *(const float4*)(pred + ro + eoff);                     \
            bet[NB] = *(const float4*)(tgt  + ro + eoff);                     \
            bem[NB] = *(const int4*)(mask + ro + eoff);                       \
        }                                                                     \
    }

    PREFETCH(0, h0 - 1)                   // row h0-1 into buffer 0

#define STEP(I)                                                               \
    {                                                                         \
        constexpr int i  = (I);                                               \
        constexpr int cb = i & 1;         /* consume buffer */                \
        constexpr int s2 = i % 3;         /* window slot for incoming row */  \
        constexpr int s1 = (i + 2) % 3;   /* row i-1 */                       \
        constexpr int s0 = (i + 1) % 3;   /* row i-2 */                       \
        const int hin = h0 - 1 + i;                                           \
        if constexpr (i < NIT - 1) PREFETCH(cb ^ 1, hin + 1)                  \
        const float4 d  = SUB4(bp[cb], bt[cb]);                               \
        const float4 ed = SUB4(bep[cb], bet[cb]);                             \
        const unsigned m  = (unsigned)(bm[cb].x | (bm[cb].y << 1) |           \
                                       (bm[cb].z << 2) | (bm[cb].w << 3));    \
        const unsigned em = (unsigned)(bem[cb].x | (bem[cb].y << 1) |         \
                                       (bem[cb].z << 2) | (bem[cb].w << 3));  \
        float4 dl, dr;                                                        \
        dl.x = __shfl_up(d.x, 2);   dl.y = __shfl_up(d.y, 2);                 \
        dl.z = __shfl_up(d.z, 2);   dl.w = __shfl_up(d.w, 2);                 \
        dr.x = __shfl_down(d.x, 2); dr.y = __shfl_down(d.y, 2);               \
        dr.z = __shfl_down(d.z, 2); dr.w = __shfl_down(d.w, 2);               \
        unsigned ml = (unsigned)__shfl_up((int)m, 2);                         \
        unsigned mr = (unsigned)__shfl_down((int)m, 2);                       \
        if (eL) { dl = ed; ml = em; }                                         \
        if (eR) { dr = ed; mr = em; }                                         \
        hx[s2] = SUB4(dr, dl);                                                \
        hs[s2] = make_float4(dl.x + 2.f * d.x + dr.x,                         \
                             dl.y + 2.f * d.y + dr.y,                         \
                             dl.z + 2.f * d.z + dr.z,                         \
                             dl.w + 2.f * d.w + dr.w);                        \
        hm[s2] = ml & m & mr;                                                 \
        if constexpr (i >= 2) {                                               \
            const int r = hin - 1;        /* output row h0 + i - 2 */         \
            unsigned vm = hm[0] & hm[1] & hm[2];                              \
            if (!win || r == 0 || r == H - 1) vm = 0u;                        \
            f32x4 o;                                                          \
            { const float gx = hx[s0].x + 2.f * hx[s1].x + hx[s2].x;          \
              const float gy = hs[s2].x - hs[s0].x;                           \
              o.x = (vm & 1u) ? (fabsf(gx) + fabsf(gy)) : 0.f; }              \
            { const float gx = hx[s0].y + 2.f * hx[s1].y + hx[s2].y;          \
              const float gy = hs[s2].y - hs[s0].y;                           \
              o.y = (vm & 2u) ? (fabsf(gx) + fabsf(gy)) : 0.f; }              \
            { const float gx = hx[s0].z + 2.f * hx[s1].z + hx[s2].z;          \
              const float gy = hs[s2].z - hs[s0].z;                           \
              o.z = (vm & 4u) ? (fabsf(gx) + fabsf(gy)) : 0.f; }              \
            { const float gx = hx[s0].w + 2.f * hx[s1].w + hx[s2].w;          \
              const float gy = hs[s2].w - hs[s0].w;                           \
              o.w = (vm & 8u) ? (fabsf(gx) + fabsf(gy)) : 0.f; }              \
            __builtin_nontemporal_store(o,                                    \
                (f32x4*)(out + ibase + (size_t)r * (W * F) + voff));          \
        }                                                                     \
    }

    STEP(0) STEP(1) STEP(2) STEP(3) STEP(4)
    STEP(5) STEP(6) STEP(7) STEP(8) STEP(9)

#undef STEP
#undef PREFETCH
#undef SUB4
}

extern "C" void kernel_launch(void* const* d_in, const int* in_sizes, int n_in,
                              void* d_out, int out_size, void* d_ws, size_t ws_size,
                              hipStream_t stream) {
    const float* pred = (const float*)d_in[0];
    const float* tgt  = (const float*)d_in[1];
    const int*   mask = (const int*)d_in[2];
    float*       out  = (float*)d_out;

    const int blocks = IMAGES * 4 * STRIPS;   // 12 * 4 * 64 = 3072
    sobel_loss_kernel<<<blocks, 256, 0, stream>>>(pred, tgt, mask, out);
}